// Round 11
// baseline (60.794 us; speedup 1.0000x reference)
//
#include <hip/hip_runtime.h>
#include <hip/hip_cooperative_groups.h>

namespace cg = cooperative_groups;

// Problem geometry (fixed by reference):
//   preds : (B=2, T=8, E=16, H=128, W=256) f32, idx ((b*8+t)*16+e)*HW + hw
//   target: (B=2, T=8, 1,    H=128, W=256) f32
//   output: scalar f32
//
// Ledger (R1-R10):
//  - Best mapping: t-pair/thread, k in low 2 lane bits, shfl boundary
//    exchange, every element loaded once (R4, 13.48us).
//  - Traffic cut (R4), load-instr cut (R8), VALU cut (R9): all ~neutral ->
//    partial body is near its latency/BW envelope.
//  - hipMemsetAsync node in graph = ~40us penalty (R10, ord-213 fill).
//  - Last-block reduce tail (is_last+fence) spills cur[] (R5/R6, VGPR 20-24);
//    bare atomic tail does NOT spill (R10).
//  - R11: single cooperative dispatch. 512 blk x 512 thr = exactly 2
//    blocks/CU co-resident; launch_bounds(512,4) = 128-VGPR budget (body
//    needs ~105). Block sums via plain stores, grid.sync(), block 0 reduces.
#define HW    32768   // 128*256
#define T_DIM 8
#define E_DIM 16
#define NPOS  65536   // B * HW
#define BLK   512
#define NBLK  512     // 262144 threads total: one per (b,hw,t-pair)

// term1/16 - term2core/256 for one (b,t,hw): p[16] vs tgt
__device__ __forceinline__ float crps_term(const float* p, float tgt) {
    float t1 = 0.f;
#pragma unroll
    for (int e = 0; e < E_DIM; ++e)
        t1 += fabsf(p[e] - tgt);
    float s = 0.f;
#pragma unroll
    for (int i = 0; i < E_DIM; ++i)
#pragma unroll
        for (int j = i + 1; j < E_DIM; ++j)
            s += fabsf(p[i] - p[j]);
    return t1 * (1.f / 16.f) - s * (1.f / 256.f);
}

__global__ __launch_bounds__(BLK, 4) void crps_coop(const float* __restrict__ preds,
                                                    const float* __restrict__ target,
                                                    float* __restrict__ partials,
                                                    float* __restrict__ out) {
    const int n  = blockIdx.x * BLK + threadIdx.x;   // 18 bits
    const int k  = n & 3;                            // t-pair 0..3 (lane bits)
    const int hw = (n >> 2) & (HW - 1);              // 15 bits
    const int b  = n >> 17;                          // 0..1
    const int t0 = 2 * k;

    const float* pb = preds  + hw;
    const float* tb = target + hw;

    float cur0[E_DIM], cur1[E_DIM];
#pragma unroll
    for (int e = 0; e < E_DIM; ++e)
        cur0[e] = pb[((size_t)((b * T_DIM + t0) * E_DIM) + e) * HW];
#pragma unroll
    for (int e = 0; e < E_DIM; ++e)
        cur1[e] = pb[((size_t)((b * T_DIM + t0 + 1) * E_DIM) + e) * HW];
    const float tgt0 = tb[(size_t)(b * T_DIM + t0) * HW];
    const float tgt1 = tb[(size_t)(b * T_DIM + t0 + 1) * HW];

    // boundary transition t=2k-1 -> 2k: pull neighbor lane's cur1
    const int lane = threadIdx.x & 63;
    const int src  = (lane > 0) ? (lane - 1) : 0;
    float tacc = 0.f;
#pragma unroll
    for (int e = 0; e < E_DIM; ++e) {
        float pv = __shfl(cur1[e], src, 64);         // exec-sync, DS pipe
        if (k > 0)
            tacc += fabsf(cur0[e] - pv);
    }
    // within-pair transition t=2k -> 2k+1
#pragma unroll
    for (int e = 0; e < E_DIM; ++e)
        tacc += fabsf(cur1[e] - cur0[e]);

    float acc = crps_term(cur0, tgt0) + crps_term(cur1, tgt1);

    // per-(b,hw) scaling: crps terms averaged over 8 t; temporal over 112
    float v = acc * (1.f / 8.f) + tacc * (0.1f / 112.f);

    // block reduction: 8 waves -> LDS
    __shared__ float rlds[8];
#pragma unroll
    for (int off = 32; off; off >>= 1)
        v += __shfl_down(v, off, 64);
    const int wid = threadIdx.x >> 6;
    if (lane == 0) rlds[wid] = v;
    __syncthreads();
    if (threadIdx.x == 0) {
        float bsum = 0.f;
#pragma unroll
        for (int i = 0; i < 8; ++i)
            bsum += rlds[i];
        partials[blockIdx.x] = bsum;
    }

    cg::this_grid().sync();

    if (blockIdx.x == 0) {
        float v2 = partials[threadIdx.x];            // 512 partials, 1 each
#pragma unroll
        for (int off = 32; off; off >>= 1)
            v2 += __shfl_down(v2, off, 64);
        __shared__ float flds[8];
        if (lane == 0) flds[wid] = v2;
        __syncthreads();
        if (threadIdx.x == 0) {
            float total = 0.f;
#pragma unroll
            for (int i = 0; i < 8; ++i)
                total += flds[i];
            out[0] = total * (1.f / (float)NPOS);
        }
    }
}

extern "C" void kernel_launch(void* const* d_in, const int* in_sizes, int n_in,
                              void* d_out, int out_size, void* d_ws, size_t ws_size,
                              hipStream_t stream) {
    const float* preds  = (const float*)d_in[0];
    const float* target = (const float*)d_in[1];
    float* out      = (float*)d_out;
    float* partials = (float*)d_ws;   // 512 floats = 2 KB scratch

    void* args[] = {(void*)&preds, (void*)&target, (void*)&partials, (void*)&out};
    hipLaunchCooperativeKernel((const void*)crps_coop, dim3(NBLK), dim3(BLK),
                               args, 0, stream);
}

// Round 12
// 19.158 us; speedup vs baseline: 3.1733x; 3.1733x over previous
//
#include <hip/hip_runtime.h>

// Problem geometry (fixed by reference):
//   preds : (B=2, T=8, E=16, H=128, W=256) f32, idx ((b*8+t)*16+e)*HW + hw
//   target: (B=2, T=8, 1,    H=128, W=256) f32
//   output: scalar f32
//
// Ledger (R1-R11):
//  - Best mapping: t-pair/thread, k in low 2 lane bits, shfl boundary
//    exchange, every element loaded once (R4, 13.48us).
//  - Traffic cut (R4), load-instr cut (R8), VALU cut (R9): all ~neutral.
//    Timed replays are L3-warm (hbm_bytes~0) and the same speed as cold
//    profile passes -> latency/issue/overhead bound, not bytes.
//  - Any reduce-tail after a sync point (last-block R5/R6, coop grid.sync
//    R11) => allocator spills cur[] (VGPR 20-24, 3-5x). Two kernels only.
//  - hipMemsetAsync node in graph = +14us (R10). No memset nodes.
//  - R12: partial uses 1 wave/block (BLK=64): no LDS, no barrier in the
//    hot kernel; 4096 blocks = 16/CU = 4 waves/SIMD (same occupancy).
//    Final: 1024 threads, one float4 each (coalesced 16KB, 1 latency round).
#define HW    32768   // 128*256
#define T_DIM 8
#define E_DIM 16
#define NPOS  65536   // B * HW
#define BLK   64      // one wave per block
#define NTHREADS 262144                 // B * HW * 4 t-pairs
#define NBLK  (NTHREADS / BLK)          // 4096
#define FBLK  1024    // final kernel threads

// term1/16 - term2core/256 for one (b,t,hw): p[16] vs tgt
__device__ __forceinline__ float crps_term(const float* p, float tgt) {
    float t1 = 0.f;
#pragma unroll
    for (int e = 0; e < E_DIM; ++e)
        t1 += fabsf(p[e] - tgt);
    float s = 0.f;
#pragma unroll
    for (int i = 0; i < E_DIM; ++i)
#pragma unroll
        for (int j = i + 1; j < E_DIM; ++j)
            s += fabsf(p[i] - p[j]);
    return t1 * (1.f / 16.f) - s * (1.f / 256.f);
}

// Thread (b, hw, k) owns t in {2k, 2k+1}; k lives in the low 2 lane bits so
// the thread holding pair k-1 (same hw) is lane-1 -> boundary temporal diffs
// via __shfl. Every preds/target element is loaded exactly once.
__global__ __launch_bounds__(BLK) void crps_partial(const float* __restrict__ preds,
                                                    const float* __restrict__ target,
                                                    float* __restrict__ partials) {
    const int n  = blockIdx.x * BLK + threadIdx.x;   // 18 bits
    const int k  = n & 3;                            // t-pair 0..3 (lane bits)
    const int hw = (n >> 2) & (HW - 1);              // 15 bits
    const int b  = n >> 17;                          // 0..1
    const int t0 = 2 * k;

    const float* pb = preds  + hw;
    const float* tb = target + hw;

    float cur0[E_DIM], cur1[E_DIM];
#pragma unroll
    for (int e = 0; e < E_DIM; ++e)
        cur0[e] = pb[((size_t)((b * T_DIM + t0) * E_DIM) + e) * HW];
#pragma unroll
    for (int e = 0; e < E_DIM; ++e)
        cur1[e] = pb[((size_t)((b * T_DIM + t0 + 1) * E_DIM) + e) * HW];
    const float tgt0 = tb[(size_t)(b * T_DIM + t0) * HW];
    const float tgt1 = tb[(size_t)(b * T_DIM + t0 + 1) * HW];

    // boundary transition t=2k-1 -> 2k: pull neighbor lane's cur1
    const int lane = threadIdx.x;                    // BLK==64: tid is lane
    const int src  = (lane > 0) ? (lane - 1) : 0;
    float tacc = 0.f;
#pragma unroll
    for (int e = 0; e < E_DIM; ++e) {
        float pv = __shfl(cur1[e], src, 64);         // exec-sync, DS pipe
        if (k > 0)
            tacc += fabsf(cur0[e] - pv);
    }
    // within-pair transition t=2k -> 2k+1
#pragma unroll
    for (int e = 0; e < E_DIM; ++e)
        tacc += fabsf(cur1[e] - cur0[e]);

    float acc = crps_term(cur0, tgt0) + crps_term(cur1, tgt1);

    // per-(b,hw) scaling: crps terms averaged over 8 t; temporal over 112
    float v = acc * (1.f / 8.f) + tacc * (0.1f / 112.f);

    // wave-level reduction only: no LDS, no barrier
#pragma unroll
    for (int off = 32; off; off >>= 1)
        v += __shfl_down(v, off, 64);
    if (lane == 0)
        partials[blockIdx.x] = v;
}

__global__ __launch_bounds__(FBLK) void crps_final(const float* __restrict__ partials,
                                                   float* __restrict__ out) {
    // 4096 partials, 1024 threads: one coalesced float4 per thread
    float4 p4 = ((const float4*)partials)[threadIdx.x];
    float v = (p4.x + p4.y) + (p4.z + p4.w);
#pragma unroll
    for (int off = 32; off; off >>= 1)
        v += __shfl_down(v, off, 64);
    __shared__ float lds[16];
    const int lane = threadIdx.x & 63;
    const int wid  = threadIdx.x >> 6;
    if (lane == 0) lds[wid] = v;
    __syncthreads();
    if (threadIdx.x == 0) {
        float total = 0.f;
#pragma unroll
        for (int i = 0; i < 16; ++i)
            total += lds[i];
        out[0] = total * (1.f / (float)NPOS);
    }
}

extern "C" void kernel_launch(void* const* d_in, const int* in_sizes, int n_in,
                              void* d_out, int out_size, void* d_ws, size_t ws_size,
                              hipStream_t stream) {
    const float* preds  = (const float*)d_in[0];
    const float* target = (const float*)d_in[1];
    float* out      = (float*)d_out;
    float* partials = (float*)d_ws;   // 4096 floats = 16 KB scratch

    crps_partial<<<NBLK, BLK, 0, stream>>>(preds, target, partials);
    crps_final<<<1, FBLK, 0, stream>>>(partials, out);
}